// Round 8
// baseline (1072.100 us; speedup 1.0000x reference)
//
#include <hip/hip_runtime.h>
#include <math.h>
#include <stdint.h>

#define N_NODES 100000
#define N_FEAT  512
#define HIDDEN  256
#define N_CLS   40
#define N_EDGES 1600000
#define K_HOPS  10

#define NPART   8                    // src partitions for L2-locality edge ordering
#define PSZ     12500                // nodes per src-part
#define NPN     (NPART * N_NODES)    // 800000 virtual CSR rows (dst, src_part)
#define SCANB   782                  // ceil((NPN+1)/1024)
#define HPAD    64                   // padded h row: 64 bf16 = 128 B

#define PB      51                   // nodes per prop block
#define PGRID   ((N_NODES + PB - 1) / PB)   // 1961
#define ECAP    1024                 // LDS epair slots (block avg ~870, 5-sigma < 1024)

typedef __attribute__((ext_vector_type(8))) short short8;   // 8 bf16
typedef __attribute__((ext_vector_type(4))) float f4_t;

__device__ __forceinline__ short f2bf(float f) {
    union { float f; unsigned u; } x; x.f = f;
    unsigned r = x.u + 0x7fffu + ((x.u >> 16) & 1u);  // RNE
    return (short)(r >> 16);
}

__device__ __forceinline__ float bf2f(short b) {
    union { unsigned u; float f; } x;
    x.u = ((unsigned)(unsigned short)b) << 16;
    return x.f;
}

// packed f32x2 -> bf16x2 (RNE), single HW instr; no builtin on gfx950
__device__ __forceinline__ unsigned cvtpk(float lo, float hi) {
    unsigned r;
    asm("v_cvt_pk_bf16_f32 %0, %1, %2" : "=v"(r) : "v"(lo), "v"(hi));
    return r;
}

// ---------------------------------------------------------------- prep kernels

__global__ __launch_bounds__(256) void init_degp_kernel(int* __restrict__ degp) {
    int idx = blockIdx.x * 256 + threadIdx.x;
    if (idx < NPN) {
        int v = idx >> 3, p = idx & 7;
        degp[idx] = (p == v / PSZ) ? 1 : 0;
    }
}

__global__ __launch_bounds__(256) void count_dst_kernel(const int* __restrict__ src,
                                                        const int* __restrict__ dst,
                                                        int* __restrict__ degp) {
    int e = blockIdx.x * 256 + threadIdx.x;
    if (e < N_EDGES) atomicAdd(&degp[dst[e] * NPART + src[e] / PSZ], 1);
}

__global__ __launch_bounds__(256) void rsqrt_deg_kernel(const int* __restrict__ degp,
                                                        float* __restrict__ d) {
    int v = blockIdx.x * 256 + threadIdx.x;
    if (v < N_NODES) {
        int s = 0;
#pragma unroll
        for (int p = 0; p < NPART; ++p) s += degp[v * NPART + p];
        d[v] = rsqrtf((float)s);
    }
}

// ---- 3-phase device-wide exclusive scan of degp -> rowptrp/cursor

__global__ __launch_bounds__(1024) void scan_partial_kernel(const int* __restrict__ degp,
                                                            int* __restrict__ blocksum) {
    __shared__ int s[1024];
    int t = threadIdx.x;
    int idx = blockIdx.x * 1024 + t;
    s[t] = (idx < NPN) ? degp[idx] : 0;
    __syncthreads();
#pragma unroll
    for (int off = 512; off > 0; off >>= 1) {
        if (t < off) s[t] += s[t + off];
        __syncthreads();
    }
    if (t == 0) blocksum[blockIdx.x] = s[0];
}

__global__ __launch_bounds__(1024) void scan_blocks_kernel(const int* __restrict__ blocksum,
                                                           int* __restrict__ blockoff) {
    __shared__ int s[1024];
    int t = threadIdx.x;
    int v = (t < SCANB) ? blocksum[t] : 0;
    s[t] = v;
    __syncthreads();
#pragma unroll
    for (int off = 1; off < 1024; off <<= 1) {
        int add = (t >= off) ? s[t - off] : 0;
        __syncthreads();
        s[t] += add;
        __syncthreads();
    }
    if (t < SCANB) blockoff[t] = s[t] - v;  // exclusive
}

__global__ __launch_bounds__(1024) void scan_write_kernel(const int* __restrict__ degp,
                                                          const int* __restrict__ blockoff,
                                                          int* __restrict__ rowptrp,
                                                          int* __restrict__ cursor) {
    __shared__ int s[1024];
    int t = threadIdx.x;
    int idx = blockIdx.x * 1024 + t;
    int v = (idx < NPN) ? degp[idx] : 0;
    s[t] = v;
    __syncthreads();
#pragma unroll
    for (int off = 1; off < 1024; off <<= 1) {
        int add = (t >= off) ? s[t - off] : 0;
        __syncthreads();
        s[t] += add;
        __syncthreads();
    }
    int pre = s[t] - v + blockoff[blockIdx.x];  // exclusive prefix
    if (idx <= NPN) rowptrp[idx] = pre;
    if (idx < NPN) cursor[idx] = pre;
}

// epair.x holds PRE-SCALED byte offset (u*128) so prop needs no multiply
__global__ __launch_bounds__(256) void scatter_edges_kernel(const int* __restrict__ src,
                                                            const int* __restrict__ dst,
                                                            const float* __restrict__ d,
                                                            int* __restrict__ cursor,
                                                            int2* __restrict__ epair) {
    int e = blockIdx.x * 256 + threadIdx.x;
    if (e >= N_EDGES) return;
    int u = src[e], v = dst[e];
    int pos = atomicAdd(&cursor[v * NPART + u / PSZ], 1);
    int2 p;
    p.x = u * 128;
    p.y = __float_as_int(d[u] * d[v]);
    epair[pos] = p;
}

__global__ __launch_bounds__(256) void scatter_self_kernel(const float* __restrict__ d,
                                                           int* __restrict__ cursor,
                                                           int2* __restrict__ epair) {
    int v = blockIdx.x * 256 + threadIdx.x;
    if (v >= N_NODES) return;
    int pos = atomicAdd(&cursor[v * NPART + v / PSZ], 1);
    float dv = d[v];
    int2 p;
    p.x = v * 128;
    p.y = __float_as_int(dv * dv);
    epair[pos] = p;
}

// W1 [512][256] f32 -> W1T [256][512] bf16 (col-major: per-col k contiguous)
__global__ __launch_bounds__(256) void cvt_w1_kernel(const float* __restrict__ W1,
                                                     short* __restrict__ W1T) {
    int lin = blockIdx.x * 256 + threadIdx.x;  // 131072
    int k = lin >> 8, n = lin & 255;
    W1T[n * 512 + k] = f2bf(W1[lin]);
}

// W2 [256][40] f32 -> W2T [64][256] bf16, rows >=40 zero
__global__ __launch_bounds__(256) void cvt_w2_kernel(const float* __restrict__ W2,
                                                     short* __restrict__ W2T) {
    int lin = blockIdx.x * 256 + threadIdx.x;  // 16384
    int n = lin >> 8, k = lin & 255;
    W2T[lin] = (n < N_CLS) ? f2bf(W2[k * N_CLS + n]) : (short)0;
}

// ---------------------------------------------------------------- fused MLP (MFMA)
// r5/r7 best-measured variant, unchanged. Block = 256 thr (4 waves), 64 rows.
__global__ __launch_bounds__(256) void mlp_kernel(const float* __restrict__ feat,
                                                  const short* __restrict__ W1T,
                                                  const float* __restrict__ b1,
                                                  const short* __restrict__ W2T,
                                                  const float* __restrict__ b2,
                                                  const float* __restrict__ temp,
                                                  short* __restrict__ h,
                                                  float* __restrict__ TH) {
    __shared__ union {
        short A[2][64][72];                                // 18432 B (K-loop)
        short sH[64][264];                                 // 33792 B (phase B in)
        struct { short Ho[64][40]; float To[64][40]; } o;  // 15360 B (epilogue)
    } S;

    const int tid = threadIdx.x;
    const int rbase = blockIdx.x * 64;
    const int lane = tid & 63;
    const int wv = tid >> 6;       // wave 0..3
    const int quad = lane >> 4;    // 0..3
    const int l15 = lane & 15;

    f4_t acc[4][4];
#pragma unroll
    for (int m = 0; m < 4; ++m)
#pragma unroll
        for (int n = 0; n < 4; ++n) acc[m][n] = (f4_t)0.f;

    const int srow = tid >> 2;
    const int scol = (tid & 3) * 16;
    int growc = rbase + srow;
    if (growc >= N_NODES) growc = N_NODES - 1;
    const float* fp = feat + (size_t)growc * N_FEAT + scol;

    f4_t fR0, fR1, fR2, fR3;
    short8 bR[8];

#define LOADF(KT)                                                   \
    { const f4_t* p_ = (const f4_t*)(fp + (KT) * 64);               \
      fR0 = p_[0]; fR1 = p_[1]; fR2 = p_[2]; fR3 = p_[3]; }

#define LOADB(KT)                                                   \
    { const short* wb_ = W1T + (KT) * 64;                           \
      _Pragma("unroll")                                             \
      for (int kk2 = 0; kk2 < 2; ++kk2)                             \
          _Pragma("unroll")                                         \
          for (int n = 0; n < 4; ++n)                               \
              bR[kk2 * 4 + n] = *(const short8*)(                   \
                  wb_ + (wv * 64 + n * 16 + l15) * 512 + kk2 * 32 + quad * 8); }

#define CVTWR(BUF)                                                  \
    { union { unsigned u[4]; short8 s; } xlo_, xhi_;                \
      xlo_.u[0] = cvtpk(fR0[0], fR0[1]); xlo_.u[1] = cvtpk(fR0[2], fR0[3]); \
      xlo_.u[2] = cvtpk(fR1[0], fR1[1]); xlo_.u[3] = cvtpk(fR1[2], fR1[3]); \
      xhi_.u[0] = cvtpk(fR2[0], fR2[1]); xhi_.u[1] = cvtpk(fR2[2], fR2[3]); \
      xhi_.u[2] = cvtpk(fR3[0], fR3[1]); xhi_.u[3] = cvtpk(fR3[2], fR3[3]); \
      short8* dp_ = (short8*)&S.A[BUF][srow][scol];                 \
      dp_[0] = xlo_.s; dp_[1] = xhi_.s; }

#define BARRIER()                                                   \
    asm volatile("s_waitcnt lgkmcnt(0)" ::: "memory");              \
    __builtin_amdgcn_s_barrier();                                   \
    __builtin_amdgcn_sched_barrier(0);

    LOADF(0);
    LOADB(0);
    CVTWR(0);
    LOADF(1);
    BARRIER();

#pragma unroll
    for (int kt = 0; kt < 8; ++kt) {
        const int cb = kt & 1;
#pragma unroll
        for (int kk2 = 0; kk2 < 2; ++kk2) {
            short8 af[4];
#pragma unroll
            for (int m = 0; m < 4; ++m)
                af[m] = *(const short8*)&S.A[cb][m * 16 + l15][kk2 * 32 + quad * 8];
#pragma unroll
            for (int m = 0; m < 4; ++m)
#pragma unroll
                for (int n = 0; n < 4; ++n)
                    acc[m][n] = __builtin_amdgcn_mfma_f32_16x16x32_bf16(
                        af[m], bR[kk2 * 4 + n], acc[m][n], 0, 0, 0);
        }
        if (kt < 7) {
            LOADB(kt + 1);
            CVTWR(cb ^ 1);
        }
        if (kt < 6) LOADF(kt + 2);
        BARRIER();
    }
#undef LOADF
#undef LOADB
#undef CVTWR

#pragma unroll
    for (int n = 0; n < 4; ++n) {
        int col = wv * 64 + n * 16 + l15;
        float bb = b1[col];
#pragma unroll
        for (int m = 0; m < 4; ++m)
#pragma unroll
            for (int r = 0; r < 4; ++r) {
                float v = acc[m][n][r] + bb;
                S.sH[m * 16 + quad * 4 + r][col] = f2bf(v > 0.f ? v : 0.f);
            }
    }
    __syncthreads();

    f4_t accB[3];
#pragma unroll
    for (int n = 0; n < 3; ++n) accB[n] = (f4_t)0.f;
#pragma unroll
    for (int kk = 0; kk < 256; kk += 32) {
        short8 a = *(const short8*)&S.sH[wv * 16 + l15][kk + quad * 8];
#pragma unroll
        for (int n = 0; n < 3; ++n) {
            short8 b = *(const short8*)(W2T + (n * 16 + l15) * 256 + kk + quad * 8);
            accB[n] = __builtin_amdgcn_mfma_f32_16x16x32_bf16(a, b, accB[n], 0, 0, 0);
        }
    }
    __syncthreads();

    float t0 = temp[0];
#pragma unroll
    for (int n = 0; n < 3; ++n) {
        int col = n * 16 + l15;
        if (col < N_CLS) {
            float bb = b2[col];
#pragma unroll
            for (int r = 0; r < 4; ++r) {
                int row = wv * 16 + quad * 4 + r;
                float v = accB[n][r] + bb;
                S.o.Ho[row][col] = f2bf(v);
                S.o.To[row][col] = t0 * v;
            }
        }
    }
    __syncthreads();

    int rows = N_NODES - rbase; if (rows > 64) rows = 64;
    int nh = rows * 5;
    for (int i = tid; i < nh; i += 256) {
        int row = i / 5, part = i - row * 5;
        *(short8*)(h + (size_t)(rbase + row) * HPAD + part * 8) =
            *(const short8*)&S.o.Ho[row][part * 8];
    }
    int nt = rows * 10;
    for (int i = tid; i < nt; i += 256)
        *(f4_t*)(TH + (size_t)rbase * N_CLS + i * 4) =
            *(const f4_t*)((const float*)&S.o.To[0][0] + i * 4);
}

// ---------------------------------------------------------------- propagation
// EDGE-BALANCED segmented SpMM. Each 5-lane group owns an equal contiguous
// slice of the block's edge list (not one node!) -> removes the max-degree
// tail that cost ~2x. Per-edge dst-local ids (sD, binary-searched once at
// staging) drive register accumulation with LDS ds_add_f32 flushes on dst
// change (~2-3 flushes per ~20-edge slice). Gather structure unchanged:
// 5 lanes/edge merged 64B requests, 4-deep ILP, LDS-staged epair.
__global__ __launch_bounds__(256, 8) void prop_kernel(const short* __restrict__ h,
                                                      short* __restrict__ hn,
                                                      const int* __restrict__ rowptrp,
                                                      const int2* __restrict__ epair,
                                                      float* __restrict__ TH,
                                                      const float* __restrict__ temp,
                                                      int kidx) {
    __shared__ long long sE[ECAP];
    __shared__ short sD[ECAP];
    __shared__ float sAcc[PB * 40];
    __shared__ int sRP[64];

    const int t = threadIdx.x;
    const int v0 = blockIdx.x * PB;
    int nmax = N_NODES - v0; if (nmax > PB) nmax = PB;
    if (t <= nmax) sRP[t] = rowptrp[(v0 + t) * NPART];
    for (int i = t; i < PB * 40; i += 256) sAcc[i] = 0.f;
    __syncthreads();
    const int S0 = sRP[0];
    const int count = sRP[nmax] - S0;   // block-uniform

    const int g = t / 5;                // 5-lane group = edge-slice owner
    const int c = t - g * 5;            // class chunk 0..4
    const char* hB = (const char*)h + c * 16;

    f4_t a0 = (f4_t)0.f, a1 = (f4_t)0.f;
    int cur = -1;

#define FLUSH()                                                     \
    if (cur >= 0) {                                                 \
        float* ap_ = &sAcc[cur * 40 + c * 8];                       \
        _Pragma("unroll")                                           \
        for (int i = 0; i < 4; ++i) {                               \
            atomicAdd(ap_ + i, a0[i]);                              \
            atomicAdd(ap_ + 4 + i, a1[i]);                          \
        }                                                           \
        a0 = (f4_t)0.f; a1 = (f4_t)0.f;                             \
    }

#define PROC(D, W, HV)                                              \
    { int d_ = (D);                                                 \
      if (d_ != cur) { FLUSH(); cur = d_; }                         \
      float w_ = (W);                                               \
      _Pragma("unroll")                                             \
      for (int i = 0; i < 4; ++i) {                                 \
          a0[i] += w_ * bf2f((HV)[i]);                              \
          a1[i] += w_ * bf2f((HV)[4 + i]);                          \
      } }

    for (int base = 0; base < count; base += ECAP) {
        int lim = count - base; if (lim > ECAP) lim = ECAP;
        // stage epair slice + dst-local id (6-step binary search over sRP)
        for (int i = t; i < lim; i += 256) {
            sE[i] = *(const long long*)(epair + (size_t)(S0 + base + i));
            int gidx = S0 + base + i;
            int lo = 0, hi2 = nmax;
            while (hi2 - lo > 1) {
                int mid = (lo + hi2) >> 1;
                if (sRP[mid] <= gidx) lo = mid; else hi2 = mid;
            }
            sD[i] = (short)lo;
        }
        __syncthreads();
        int lo_e = 0, hi_e = 0;
        if (t < 255) { lo_e = (g * lim) / PB; hi_e = ((g + 1) * lim) / PB; }
        int jj = lo_e;
        for (; jj + 4 <= hi_e; jj += 4) {
            long long r0 = sE[jj], r1 = sE[jj + 1], r2 = sE[jj + 2], r3 = sE[jj + 3];
            int d0 = sD[jj], d1 = sD[jj + 1], d2 = sD[jj + 2], d3 = sD[jj + 3];
            short8 h0 = *(const short8*)(hB + (unsigned)(int)r0);
            short8 h1 = *(const short8*)(hB + (unsigned)(int)r1);
            short8 h2 = *(const short8*)(hB + (unsigned)(int)r2);
            short8 h3 = *(const short8*)(hB + (unsigned)(int)r3);
            float w0 = __int_as_float((int)(r0 >> 32));
            float w1 = __int_as_float((int)(r1 >> 32));
            float w2 = __int_as_float((int)(r2 >> 32));
            float w3 = __int_as_float((int)(r3 >> 32));
            PROC(d0, w0, h0);
            PROC(d1, w1, h1);
            PROC(d2, w2, h2);
            PROC(d3, w3, h3);
        }
        for (; jj < hi_e; ++jj) {
            long long r = sE[jj];
            int d = sD[jj];
            short8 hv = *(const short8*)(hB + (unsigned)(int)r);
            float w = __int_as_float((int)(r >> 32));
            PROC(d, w, hv);
        }
        FLUSH();
        cur = -1;
        __syncthreads();   // atomics drained; sE/sD safe to restage
    }
#undef PROC
#undef FLUSH

    // write-out: group g owns node v0+g; read full sums from sAcc
    if (t < 255 && g < nmax) {
        int v = v0 + g;
        float tk = temp[kidx];
        const float* ap = &sAcc[g * 40 + c * 8];
        f4_t r0v, r1v;
#pragma unroll
        for (int i = 0; i < 4; ++i) { r0v[i] = ap[i]; r1v[i] = ap[4 + i]; }
        short8 ob;
#pragma unroll
        for (int i = 0; i < 4; ++i) { ob[i] = f2bf(r0v[i]); ob[4 + i] = f2bf(r1v[i]); }
        *(short8*)(hn + (size_t)v * HPAD + c * 8) = ob;
        float* pt = TH + (size_t)v * N_CLS + c * 8;
        f4_t t0v = *(const f4_t*)pt;
        f4_t t1v = *(((const f4_t*)pt) + 1);
        t0v += tk * r0v;
        t1v += tk * r1v;
        *(f4_t*)pt = t0v;
        *(((f4_t*)pt) + 1) = t1v;
    }
}

// ---------------------------------------------------------------- log_softmax
__global__ __launch_bounds__(256) void lsm_kernel(float* __restrict__ out) {
    int wid = (blockIdx.x * 256 + threadIdx.x) >> 6;
    int lane = threadIdx.x & 63;
    if (wid >= N_NODES) return;
    float x = (lane < N_CLS) ? out[wid * N_CLS + lane] : -INFINITY;
    float m = x;
#pragma unroll
    for (int o = 32; o > 0; o >>= 1) m = fmaxf(m, __shfl_xor(m, o, 64));
    float e = (lane < N_CLS) ? expf(x - m) : 0.f;
    float s = e;
#pragma unroll
    for (int o = 32; o > 0; o >>= 1) s += __shfl_xor(s, o, 64);
    float r = x - m - logf(s);
    if (lane < N_CLS) out[wid * N_CLS + lane] = r;
}

// ---------------------------------------------------------------- launch

extern "C" void kernel_launch(void* const* d_in, const int* in_sizes, int n_in,
                              void* d_out, int out_size, void* d_ws, size_t ws_size,
                              hipStream_t stream) {
    const float* feat = (const float*)d_in[0];
    const float* W1   = (const float*)d_in[1];
    const float* b1   = (const float*)d_in[2];
    const float* W2   = (const float*)d_in[3];
    const float* b2   = (const float*)d_in[4];
    const float* temp = (const float*)d_in[5];
    const int*   src  = (const int*)d_in[6];
    const int*   dst  = (const int*)d_in[7];
    float* out = (float*)d_out;

    // workspace layout (bytes). degp region reused for W1T/W2T after scan_write.
    char* ws = (char*)d_ws;
    int*   degp    = (int*)(ws + 0);          // 3,200,000 B (dead after scan_write)
    short* W1T     = (short*)(ws + 0);        //   262,144 B (overlaps degp)
    short* W2T     = (short*)(ws + 262144);   //    32,768 B (overlaps degp)
    float* dnorm   = (float*)(ws + 3200000);  //   400,000 B
    int*   rowptrp = (int*)(ws + 3600000);    // 3,200,004 B
    int*   cursor  = (int*)(ws + 6800016);    // 3,200,000 B
    int2*  epair   = (int2*)(ws + 10000016);  // 13,600,000 B
    short* h0      = (short*)(ws + 23600016); // 12,800,000 B (bf16, [N][64] padded)
    short* h1      = (short*)(ws + 36400016); // 12,800,000 B
    int*   blocksum = (int*)(ws + 49200016);  //     3,128 B
    int*   blockoff = (int*)(ws + 49203152);  //     3,128 B  -> end 49,206,280

    init_degp_kernel<<<(NPN + 255) / 256, 256, 0, stream>>>(degp);
    count_dst_kernel<<<(N_EDGES + 255) / 256, 256, 0, stream>>>(src, dst, degp);
    rsqrt_deg_kernel<<<(N_NODES + 255) / 256, 256, 0, stream>>>(degp, dnorm);
    scan_partial_kernel<<<SCANB, 1024, 0, stream>>>(degp, blocksum);
    scan_blocks_kernel<<<1, 1024, 0, stream>>>(blocksum, blockoff);
    scan_write_kernel<<<SCANB, 1024, 0, stream>>>(degp, blockoff, rowptrp, cursor);
    cvt_w1_kernel<<<512, 256, 0, stream>>>(W1, W1T);
    cvt_w2_kernel<<<64, 256, 0, stream>>>(W2, W2T);
    scatter_edges_kernel<<<(N_EDGES + 255) / 256, 256, 0, stream>>>(src, dst, dnorm, cursor,
                                                                    epair);
    scatter_self_kernel<<<(N_NODES + 255) / 256, 256, 0, stream>>>(dnorm, cursor, epair);

    mlp_kernel<<<(N_NODES + 63) / 64, 256, 0, stream>>>(feat, W1T, b1, W2T, b2, temp, h0, out);

    short* hc = h0;
    short* hn = h1;
    for (int k = 0; k < K_HOPS; ++k) {
        prop_kernel<<<PGRID, 256, 0, stream>>>(hc, hn, rowptrp, epair, out, temp, k + 1);
        short* t = hc; hc = hn; hn = t;
    }

    lsm_kernel<<<(N_NODES / 4), 256, 0, stream>>>(out);
}